// Round 1
// baseline (262.027 us; speedup 1.0000x reference)
//
#include <hip/hip_runtime.h>
#include <math.h>

#define BB 8192
#define KK 32
#define DD 129      // hyperboloid dim = D + 1
#define VV 2048
#define NN 33       // K + 1
#define TOPK 10

__global__ __launch_bounds__(256) void lr_main(
    const float* __restrict__ anchor,
    const float* __restrict__ positive,
    const float* __restrict__ neg,
    const float* __restrict__ tree,
    const int* __restrict__ a_idx,
    const int* __restrict__ p_idx,
    const int* __restrict__ n_idx,
    float* __restrict__ partial)
{
    __shared__ float sA[DD];
    __shared__ float sP[DD];
    __shared__ float sR[KK * DD];      // 4128 floats = 16.5 KB
    __shared__ float sd[NN];
    __shared__ float st_[NN];
    __shared__ float srel[NN];
    __shared__ float sdisc[NN];
    __shared__ float sidcg[NN];
    __shared__ float sinv;
    __shared__ float swave[4];

    const int b = blockIdx.x;
    const int t = threadIdx.x;

    // ---- stage inputs into LDS (float4-coalesced for the 16.5 KB neg tile) ----
    {
        const float4* g4 = (const float4*)(neg + (size_t)b * (KK * DD)); // 16512 B/batch: 16B aligned
        float4* s4 = (float4*)sR;
        for (int i = t; i < (KK * DD) / 4; i += 256) s4[i] = g4[i];
    }
    for (int i = t; i < DD; i += 256) {
        sA[i] = anchor[(size_t)b * DD + i];
        sP[i] = positive[(size_t)b * DD + i];
    }
    if (t < NN) {
        int ai = a_idx[b];
        st_[t] = (t == 0)
            ? tree[(size_t)ai * VV + p_idx[b]]
            : tree[(size_t)ai * VV + n_idx[(size_t)b * KK + (t - 1)]];
    }
    __syncthreads();

    // ---- Lorentz distances: 33 dots of 129, one wave per row round-robin ----
    {
        const int wave = t >> 6;
        const int lane = t & 63;
        for (int row = wave; row < NN; row += 4) {
            const float* r = (row == 0) ? sP : (sR + (row - 1) * DD);
            float p = sA[lane] * r[lane] + sA[lane + 64] * r[lane + 64];
            if (lane == 0) p += sA[128] * r[128];
            #pragma unroll
            for (int off = 32; off > 0; off >>= 1)
                p += __shfl_xor(p, off, 64);
            if (lane == 0) {
                // -inner = u0*v0 - sum_{1..128} = 2*u0*v0 - full_dot
                float x = fmaxf(2.0f * sA[0] * r[0] - p, 1.0f + 1e-07f);
                sd[row] = acoshf(x);
            }
        }
    }
    __syncthreads();

    // ---- rel (needs max_t), rank -> disc (stable ties, matches jnp stable argsort) ----
    if (t < NN) {
        float maxt = st_[0];
        #pragma unroll
        for (int j = 1; j < NN; ++j) maxt = fmaxf(maxt, st_[j]);
        srel[t] = (maxt - st_[t] + 1e-06f) / (maxt + 1e-06f);

        float di = sd[t];
        int cnt = 0;
        #pragma unroll
        for (int j = 0; j < NN; ++j) {
            float dj = sd[j];
            cnt += (int)((dj < di) | ((dj == di) & (j < t)));
        }
        int rank = cnt + 1;
        sdisc[t] = (rank <= TOPK) ? 1.0f / log2f((float)rank + 1.0f) : 0.0f;
    }
    __syncthreads();

    // ---- ideal DCG: stable descending position of rel[t] ----
    if (t < NN) {
        float ri = srel[t];
        int pos = 0;
        #pragma unroll
        for (int j = 0; j < NN; ++j) {
            float rj = srel[j];
            pos += (int)((rj > ri) | ((rj == ri) & (j < t)));
        }
        sidcg[t] = (pos < TOPK) ? ri / log2f((float)pos + 2.0f) : 0.0f;
    }
    __syncthreads();
    if (t == 0) {
        float idcg = 0.0f;
        #pragma unroll
        for (int j = 0; j < NN; ++j) idcg += sidcg[j];
        sinv = (idcg > 0.0f) ? 1.0f / idcg : 0.0f;
    }
    __syncthreads();

    // ---- 33x33 pair sum ----
    float acc = 0.0f;
    {
        const float inv_idcg = sinv;
        for (int p = t; p < NN * NN; p += 256) {
            int i = p / NN;
            int j = p - i * NN;
            float drel  = srel[i] - srel[j];
            float ddisc = sdisc[i] - sdisc[j];
            float dd    = sd[j] - sd[i];                 // d[:,None,:] - d[:,:,None]
            float S     = (drel > 0.0f) ? 1.0f : ((drel < 0.0f) ? -1.0f : 0.0f);
            float delta = fabsf(drel * ddisc) * inv_idcg;
            float sig   = 1.0f / (1.0f + __expf(-(S * dd)));  // SIGMA = 1
            acc += S * delta * sig * (-dd);
        }
    }
    #pragma unroll
    for (int off = 32; off > 0; off >>= 1)
        acc += __shfl_xor(acc, off, 64);
    if ((t & 63) == 0) swave[t >> 6] = acc;
    __syncthreads();
    if (t == 0)
        partial[b] = 0.5f * (swave[0] + swave[1] + swave[2] + swave[3]);
}

__global__ __launch_bounds__(256) void lr_reduce(
    const float* __restrict__ partial, float* __restrict__ out)
{
    __shared__ float swave[4];
    float acc = 0.0f;
    for (int i = threadIdx.x; i < BB; i += 256) acc += partial[i];
    #pragma unroll
    for (int off = 32; off > 0; off >>= 1)
        acc += __shfl_xor(acc, off, 64);
    if ((threadIdx.x & 63) == 0) swave[threadIdx.x >> 6] = acc;
    __syncthreads();
    if (threadIdx.x == 0)
        out[0] = 0.15f * (swave[0] + swave[1] + swave[2] + swave[3]) * (1.0f / (float)BB);
}

extern "C" void kernel_launch(void* const* d_in, const int* in_sizes, int n_in,
                              void* d_out, int out_size, void* d_ws, size_t ws_size,
                              hipStream_t stream)
{
    const float* anchor   = (const float*)d_in[0];
    const float* positive = (const float*)d_in[1];
    const float* neg      = (const float*)d_in[2];
    const float* tree     = (const float*)d_in[3];
    const int*   a_idx    = (const int*)d_in[4];
    const int*   p_idx    = (const int*)d_in[5];
    const int*   n_idx    = (const int*)d_in[6];
    float* partial = (float*)d_ws;   // BB floats = 32 KB scratch

    lr_main<<<BB, 256, 0, stream>>>(anchor, positive, neg, tree,
                                    a_idx, p_idx, n_idx, partial);
    lr_reduce<<<1, 256, 0, stream>>>(partial, (float*)d_out);
}